// Round 4
// baseline (353.741 us; speedup 1.0000x reference)
//
#include <hip/hip_runtime.h>

// Problem constants (B, L_IN, D) = (4, 4096, 1024)
#define BB 4
#define LL 4096
#define DD 1024
#define SS 64   // number of chunks in the scan
#define TT 64   // chunk length (SS*TT == LL)

typedef __attribute__((ext_vector_type(16))) float  floatx16;
typedef __attribute__((ext_vector_type(8)))  short  shortx8;

static __device__ __forceinline__ unsigned short f2bf(float f) {
    unsigned int u = __float_as_uint(f);
    u += 0x7fffu + ((u >> 16) & 1u);           // round-to-nearest-even
    return (unsigned short)(u >> 16);
}
static __device__ __forceinline__ float bf2f(unsigned short h) {
    return __uint_as_float(((unsigned int)h) << 16);
}

// ---------------- merged f32 -> bf16 cast (inputs + Wi + Wo) ----------------
#define NIN4 (BB * LL * DD / 4)          // 4194304
#define NW4  (2 * DD * DD / 4)           // 524288
__global__ void cast_all_kernel(const float4* __restrict__ s_in, ushort4* __restrict__ d_inb,
                                const float4* __restrict__ s_wi, ushort4* __restrict__ d_wib,
                                const float4* __restrict__ s_wo, ushort4* __restrict__ d_wob) {
    int i = blockIdx.x * blockDim.x + threadIdx.x;
    const float4* s; ushort4* d; int j;
    if (i < NIN4)                 { s = s_in; d = d_inb; j = i; }
    else if (i < NIN4 + NW4)      { s = s_wi; d = d_wib; j = i - NIN4; }
    else                          { s = s_wo; d = d_wob; j = i - NIN4 - NW4; }
    float4 v = s[j];
    ushort4 o;
    o.x = f2bf(v.x); o.y = f2bf(v.y); o.z = f2bf(v.z); o.w = f2bf(v.w);
    d[j] = o;
}

// ---------------- bf16 GEMM: C[M,N] = A[M,K] * B[N,K]^T + bias ----------------
// m97 staging (global_load_lds w=16, XOR-swizzled LDS), XCD-aware block remap,
// compute: 2x2 of 32x32x16 MFMA per wave (vs 4x4 of 16x16x32 before).
// LDS chunk q (16B) holds row=q>>2, k8 = (q&3) ^ ((row>>1)&3).
// EPI==0: store bf16 (no relu). EPI==1: store f32 with relu.
template<int K, int NT, int EPI>
__global__ __launch_bounds__(256)
void gemm_bt(const unsigned short* __restrict__ A,
             const unsigned short* __restrict__ B,
             const float* __restrict__ bias,
             void* __restrict__ Cp) {
    constexpr int N = NT * 128;
    __shared__ __align__(16) short As[128 * 32];
    __shared__ __align__(16) short Bs[128 * 32];

    const int tid = threadIdx.x;
    const int b   = blockIdx.x;
    const int xcd = b & 7;
    const int i2  = b >> 3;
    const int tileM = ((i2 / NT) * 8 + xcd) * 128;
    const int tileN = (i2 % NT) * 128;

    const int lane = tid & 63;
    const int wave = tid >> 6;
    const int wm   = (wave >> 1) * 64;   // wave M offset within tile
    const int wn   = (wave & 1) * 64;    // wave N offset within tile
    const int r32  = lane & 31;
    const int ks   = lane >> 5;

    floatx16 acc[2][2] = {};

    // staging: lane handles chunks q0=tid, q1=tid+256; LDS dest q*16B
    // (wave-uniform base + lane*16); global source row q>>2,
    // k-chunk (q&3)^((row>>1)&3)  [XOR swizzle].
    const int q0 = tid, q1 = tid + 256;
    const int ra0 = q0 >> 2, ca0 = ((q0 & 3) ^ ((ra0 >> 1) & 3)) * 8;
    const int ra1 = q1 >> 2, ca1 = ((q1 & 3) ^ ((ra1 >> 1) & 3)) * 8;
    short* As0 = &As[(q0 & ~63) * 8];
    short* As1 = &As[(q1 & ~63) * 8];
    short* Bs0 = &Bs[(q0 & ~63) * 8];
    short* Bs1 = &Bs[(q1 & ~63) * 8];

    for (int k0 = 0; k0 < K; k0 += 32) {
        __builtin_amdgcn_global_load_lds(
            (const __attribute__((address_space(1))) void*)&A[(size_t)(tileM + ra0) * K + k0 + ca0],
            (__attribute__((address_space(3))) void*)As0, 16, 0, 0);
        __builtin_amdgcn_global_load_lds(
            (const __attribute__((address_space(1))) void*)&A[(size_t)(tileM + ra1) * K + k0 + ca1],
            (__attribute__((address_space(3))) void*)As1, 16, 0, 0);
        __builtin_amdgcn_global_load_lds(
            (const __attribute__((address_space(1))) void*)&B[(size_t)(tileN + ra0) * K + k0 + ca0],
            (__attribute__((address_space(3))) void*)Bs0, 16, 0, 0);
        __builtin_amdgcn_global_load_lds(
            (const __attribute__((address_space(1))) void*)&B[(size_t)(tileN + ra1) * K + k0 + ca1],
            (__attribute__((address_space(3))) void*)Bs1, 16, 0, 0);
        __syncthreads();

        // A-frag (32x32x16): lane holds A[m=lane&31][k = kc*16 + ks*8 + j]
        //  -> k8 = kc*2+ks, LDS slot = k8 ^ ((row>>1)&3)
        shortx8 af[2][2], bfr[2][2];
#pragma unroll
        for (int i = 0; i < 2; ++i) {
            const int row = wm + i * 32 + r32;
            const int sw  = (row >> 1) & 3;
#pragma unroll
            for (int kc = 0; kc < 2; ++kc)
                af[i][kc] = *(const shortx8*)(&As[row * 32 + ((kc * 2 + ks) ^ sw) * 8]);
        }
#pragma unroll
        for (int j = 0; j < 2; ++j) {
            const int row = wn + j * 32 + r32;
            const int sw  = (row >> 1) & 3;
#pragma unroll
            for (int kc = 0; kc < 2; ++kc)
                bfr[j][kc] = *(const shortx8*)(&Bs[row * 32 + ((kc * 2 + ks) ^ sw) * 8]);
        }
#pragma unroll
        for (int kc = 0; kc < 2; ++kc)
#pragma unroll
            for (int i = 0; i < 2; ++i)
#pragma unroll
                for (int j = 0; j < 2; ++j)
                    acc[i][j] = __builtin_amdgcn_mfma_f32_32x32x16_bf16(
                        af[i][kc], bfr[j][kc], acc[i][j], 0, 0, 0);
        __syncthreads();
    }

    // epilogue: C/D layout col=lane&31, row=(r&3)+8*(r>>2)+4*ks
#pragma unroll
    for (int i = 0; i < 2; ++i) {
#pragma unroll
        for (int j = 0; j < 2; ++j) {
            const int col = tileN + wn + j * 32 + r32;
            const float bv = bias[col];
#pragma unroll
            for (int r = 0; r < 16; ++r) {
                const int row = tileM + wm + i * 32 + (r & 3) + 8 * (r >> 2) + 4 * ks;
                float v = acc[i][j][r] + bv;
                if (EPI == 0) {
                    ((unsigned short*)Cp)[(size_t)row * N + col] = f2bf(v);
                } else {
                    ((float*)Cp)[(size_t)row * N + col] = fmaxf(v, 0.0f);
                }
            }
        }
    }
}

// ---------------- scan phase A: per-chunk local end values (2 ch/thread) ----------------
// u: bf16 [B*L, 2D] (re/im interleaved per channel). Eend: [SS][B*D] float2.
__global__ __launch_bounds__(256)
void scanA(const unsigned short* __restrict__ u,
           const float* __restrict__ plog,
           float2* __restrict__ Eend) {
    const int d0 = (blockIdx.x * 256 + threadIdx.x) * 2;
    const int c = blockIdx.y, b = blockIdx.z;
    const float v0  = expf(plog[d0]),      v1  = expf(plog[d0 + 1]);
    const float th0 = expf(plog[DD + d0]), th1 = expf(plog[DD + d0 + 1]);
    const float a0 = expf(-v0), a1 = expf(-v1);
    const float lr0 = a0 * cosf(th0), li0 = a0 * sinf(th0);
    const float lr1 = a1 * cosf(th1), li1 = a1 * sinf(th1);
    float zr0 = 0.f, zi0 = 0.f, zr1 = 0.f, zi1 = 0.f;
    const unsigned short* up = u + (size_t)(b * LL + c * TT) * (2 * DD) + 2 * d0;
#pragma unroll 4
    for (int tl = 0; tl < TT; ++tl) {
        uint2 pr = *(const uint2*)up;
        float xr0 = bf2f((unsigned short)(pr.x & 0xffffu));
        float xi0 = bf2f((unsigned short)(pr.x >> 16));
        float xr1 = bf2f((unsigned short)(pr.y & 0xffffu));
        float xi1 = bf2f((unsigned short)(pr.y >> 16));
        float t;
        t = lr0 * zr0 - li0 * zi0 + xr0; zi0 = lr0 * zi0 + li0 * zr0 + xi0; zr0 = t;
        t = lr1 * zr1 - li1 * zi1 + xr1; zi1 = lr1 * zi1 + li1 * zr1 + xi1; zr1 = t;
        up += 2 * DD;
    }
    *(float4*)&Eend[(size_t)c * (BB * DD) + b * DD + d0] =
        make_float4(zr0, zi0, zr1, zi1);
}

// ---------------- scan phase C: carry prefix + fix-up + gamma (2 ch/thread) ----------------
// xr layout: [B*L, 2D] with col d = gamma*Re(y), col DD+d = gamma*Im(y)
__global__ __launch_bounds__(256)
void scanC(const unsigned short* __restrict__ u,
           const float* __restrict__ plog,
           const float2* __restrict__ Eend,
           unsigned short* __restrict__ xr) {
    const int d0 = (blockIdx.x * 256 + threadIdx.x) * 2;
    const int c = blockIdx.y, b = blockIdx.z;
    const float v0  = expf(plog[d0]),      v1  = expf(plog[d0 + 1]);
    const float th0 = expf(plog[DD + d0]), th1 = expf(plog[DD + d0 + 1]);
    const float g0  = expf(plog[2 * DD + d0]), g1 = expf(plog[2 * DD + d0 + 1]);
    const float a0 = expf(-v0), a1 = expf(-v1);
    const float lr0 = a0 * cosf(th0), li0 = a0 * sinf(th0);
    const float lr1 = a1 * cosf(th1), li1 = a1 * sinf(th1);

    // carry into chunk c: prefix over earlier chunks with Lambda = lambda^TT
    const float aT0 = expf(-(float)TT * v0), aT1 = expf(-(float)TT * v1);
    const float Lr0 = aT0 * cosf((float)TT * th0), Li0 = aT0 * sinf((float)TT * th0);
    const float Lr1 = aT1 * cosf((float)TT * th1), Li1 = aT1 * sinf((float)TT * th1);
    float yr0 = 0.f, yi0 = 0.f, yr1 = 0.f, yi1 = 0.f;
    for (int cc = 0; cc < c; ++cc) {
        float4 e = *(const float4*)&Eend[(size_t)cc * (BB * DD) + b * DD + d0];
        float t;
        t = Lr0 * yr0 - Li0 * yi0 + e.x; yi0 = Lr0 * yi0 + Li0 * yr0 + e.y; yr0 = t;
        t = Lr1 * yr1 - Li1 * yi1 + e.z; yi1 = Lr1 * yi1 + Li1 * yr1 + e.w; yr1 = t;
    }

    const unsigned short* up = u + (size_t)(b * LL + c * TT) * (2 * DD) + 2 * d0;
    unsigned short* xp = xr + (size_t)(b * LL + c * TT) * (2 * DD) + d0;
#pragma unroll 4
    for (int tl = 0; tl < TT; ++tl) {
        uint2 pr = *(const uint2*)up;
        float xr0 = bf2f((unsigned short)(pr.x & 0xffffu));
        float xi0 = bf2f((unsigned short)(pr.x >> 16));
        float xr1 = bf2f((unsigned short)(pr.y & 0xffffu));
        float xi1 = bf2f((unsigned short)(pr.y >> 16));
        float t;
        t = lr0 * yr0 - li0 * yi0 + xr0; yi0 = lr0 * yi0 + li0 * yr0 + xi0; yr0 = t;
        t = lr1 * yr1 - li1 * yi1 + xr1; yi1 = lr1 * yi1 + li1 * yr1 + xi1; yr1 = t;
        *(unsigned int*)&xp[0]  = (unsigned int)f2bf(g0 * yr0) |
                                  ((unsigned int)f2bf(g1 * yr1) << 16);
        *(unsigned int*)&xp[DD] = (unsigned int)f2bf(g0 * yi0) |
                                  ((unsigned int)f2bf(g1 * yi1) << 16);
        up += 2 * DD;
        xp += 2 * DD;
    }
}

extern "C" void kernel_launch(void* const* d_in, const int* in_sizes, int n_in,
                              void* d_out, int out_size, void* d_ws, size_t ws_size,
                              hipStream_t stream) {
    const float* inputs = (const float*)d_in[0];   // B*L*D = 16777216
    const float* Wi     = (const float*)d_in[1];   // 2D*D  = 2097152
    const float* bi     = (const float*)d_in[2];   // 2D
    const float* Wo     = (const float*)d_in[3];   // D*2D  = 2097152
    const float* bo     = (const float*)d_in[4];   // D
    const float* plog   = (const float*)d_in[5];   // 3*D
    float* out = (float*)d_out;

    const size_t M = (size_t)BB * LL;              // 16384
    unsigned short* u_bf  = (unsigned short*)d_ws;             // M*2D bf16  (64 MB)
    unsigned short* xr_bf = u_bf  + M * 2 * DD;                // M*2D bf16  (64 MB)
    unsigned short* in_bf = xr_bf + M * 2 * DD;                // M*D  bf16  (32 MB)
    unsigned short* Wi_bf = in_bf + M * DD;                    // 2D*D bf16  (4 MB)
    unsigned short* Wo_bf = Wi_bf + (size_t)2 * DD * DD;       // D*2D bf16  (4 MB)
    float2* Eend = (float2*)(Wo_bf + (size_t)2 * DD * DD);     // SS*B*D f32x2 (2 MB)

    // merged bf16 casts (inputs + Wi + Wo) in one dispatch
    {
        int total4 = NIN4 + 2 * NW4;
        cast_all_kernel<<<total4 / 256, 256, 0, stream>>>(
            (const float4*)inputs, (ushort4*)in_bf,
            (const float4*)Wi,     (ushort4*)Wi_bf,
            (const float4*)Wo,     (ushort4*)Wo_bf);
    }

    // GEMM1: u[M, 2D] = in_bf[M, D] @ Wi^T + bi   (bf16 out), NT = 16
    gemm_bt<DD, 16, 0><<<(M / 128) * 16, 256, 0, stream>>>(
        in_bf, Wi_bf, bi, (void*)u_bf);

    // scan (2-pass chunked; carries computed inline in scanC), 2 channels/thread
    scanA<<<dim3(DD / 512, SS, BB), 256, 0, stream>>>(u_bf, plog, Eend);
    scanC<<<dim3(DD / 512, SS, BB), 256, 0, stream>>>(u_bf, plog, Eend, xr_bf);

    // GEMM2: out[M, D] = relu(xr[M, 2D] @ Wo^T + bo)  (f32 out), NT = 8
    gemm_bt<2 * DD, 8, 1><<<(M / 128) * 8, 256, 0, stream>>>(
        xr_bf, Wo_bf, bo, (void*)out);
}

// Round 5
// 336.136 us; speedup vs baseline: 1.0524x; 1.0524x over previous
//
#include <hip/hip_runtime.h>

// Problem constants (B, L_IN, D) = (4, 4096, 1024)
#define BB 4
#define LL 4096
#define DD 1024
#define SS 64   // number of chunks in the scan
#define TT 64   // chunk length (SS*TT == LL)

typedef __attribute__((ext_vector_type(4))) float  floatx4;
typedef __attribute__((ext_vector_type(8))) short  shortx8;

static __device__ __forceinline__ unsigned short f2bf(float f) {
    unsigned int u = __float_as_uint(f);
    u += 0x7fffu + ((u >> 16) & 1u);           // round-to-nearest-even
    return (unsigned short)(u >> 16);
}
static __device__ __forceinline__ float bf2f(unsigned short h) {
    return __uint_as_float(((unsigned int)h) << 16);
}

// ---------------- merged f32 -> bf16 cast (inputs + Wi + Wo) ----------------
#define NIN4 (BB * LL * DD / 4)          // 4194304
#define NW4  (2 * DD * DD / 4)           // 524288
__global__ void cast_all_kernel(const float4* __restrict__ s_in, ushort4* __restrict__ d_inb,
                                const float4* __restrict__ s_wi, ushort4* __restrict__ d_wib,
                                const float4* __restrict__ s_wo, ushort4* __restrict__ d_wob) {
    int i = blockIdx.x * blockDim.x + threadIdx.x;
    const float4* s; ushort4* d; int j;
    if (i < NIN4)                 { s = s_in; d = d_inb; j = i; }
    else if (i < NIN4 + NW4)      { s = s_wi; d = d_wib; j = i - NIN4; }
    else                          { s = s_wo; d = d_wob; j = i - NIN4 - NW4; }
    float4 v = s[j];
    ushort4 o;
    o.x = f2bf(v.x); o.y = f2bf(v.y); o.z = f2bf(v.z); o.w = f2bf(v.w);
    d[j] = o;
}

// ---------------- bf16 GEMM: C[M,N] = A[M,K] * B[N,K]^T + bias ----------------
// R3 structure (16x16x32 MFMA 4x4/wave, global_load_lds w=16, XCD remap) with
// BK=64: 32 KB LDS, half the barriers of BK=32.
// LDS chunk q (16B) holds row=q>>3, k8 = (q&7) ^ (row&7)  [3-bit XOR swizzle].
// Fragment read row stride = 64 shorts (bank-neutral); per-phase banks = 2-way (free).
// EPI==0: store bf16 (no relu). EPI==1: store f32 with relu.
template<int K, int NT, int EPI>
__global__ __launch_bounds__(256)
void gemm_bt(const unsigned short* __restrict__ A,
             const unsigned short* __restrict__ B,
             const float* __restrict__ bias,
             void* __restrict__ Cp) {
    constexpr int N = NT * 128;
    __shared__ __align__(16) short As[128 * 64];
    __shared__ __align__(16) short Bs[128 * 64];

    const int tid = threadIdx.x;
    // XCD-aware remap: blocks with equal (b&7) share an XCD; enumerate that
    // XCD's blocks as (M-tile group, all N-tiles) for A-tile L2 reuse.
    const int b   = blockIdx.x;
    const int xcd = b & 7;
    const int i2  = b >> 3;
    const int tileM = ((i2 / NT) * 8 + xcd) * 128;
    const int tileN = (i2 % NT) * 128;

    const int lane  = tid & 63;
    const int wave  = tid >> 6;
    const int wm    = (wave >> 1) * 64;   // wave M offset within tile
    const int wn    = (wave & 1) * 64;    // wave N offset within tile
    const int r16   = lane & 15;
    const int quad  = lane >> 4;

    floatx4 acc[4][4] = {};

    // staging: instruction n (n=0..3) writes chunks n*256 + wave*64 + lane
    // (wave-uniform LDS base + lane*16). Thread's chunk q = tid + n*256:
    // global row = q>>3, col8 = (q&7) ^ (row&7).
    int rowS[4], colS[4];
#pragma unroll
    for (int n = 0; n < 4; ++n) {
        const int q = tid + n * 256;
        rowS[n] = q >> 3;
        colS[n] = ((q & 7) ^ (rowS[n] & 7)) * 8;
    }
    const int ldsBase = (tid & ~63) * 8;   // shorts; + n*256*8 per instruction

    // fragment-read slot xor: slot = (kk*4+quad) ^ (r16&7)
    const int fx = r16 & 7;

    for (int k0 = 0; k0 < K; k0 += 64) {
#pragma unroll
        for (int n = 0; n < 4; ++n) {
            __builtin_amdgcn_global_load_lds(
                (const __attribute__((address_space(1))) void*)&A[(size_t)(tileM + rowS[n]) * K + k0 + colS[n]],
                (__attribute__((address_space(3))) void*)&As[ldsBase + n * 2048], 16, 0, 0);
            __builtin_amdgcn_global_load_lds(
                (const __attribute__((address_space(1))) void*)&B[(size_t)(tileN + rowS[n]) * K + k0 + colS[n]],
                (__attribute__((address_space(3))) void*)&Bs[ldsBase + n * 2048], 16, 0, 0);
        }
        __syncthreads();

#pragma unroll
        for (int kk = 0; kk < 2; ++kk) {
            const int slot = ((kk * 4 + quad) ^ fx) * 8;
            shortx8 af[4], bfv[4];
#pragma unroll
            for (int i = 0; i < 4; ++i)
                af[i] = *(const shortx8*)(&As[(wm + i * 16 + r16) * 64 + slot]);
#pragma unroll
            for (int j = 0; j < 4; ++j)
                bfv[j] = *(const shortx8*)(&Bs[(wn + j * 16 + r16) * 64 + slot]);
#pragma unroll
            for (int i = 0; i < 4; ++i)
#pragma unroll
                for (int j = 0; j < 4; ++j)
                    acc[i][j] = __builtin_amdgcn_mfma_f32_16x16x32_bf16(
                        af[i], bfv[j], acc[i][j], 0, 0, 0);
        }
        __syncthreads();
    }

    // epilogue: C row = tileM + wm + i*16 + quad*4 + r ; col = tileN + wn + j*16 + r16
#pragma unroll
    for (int i = 0; i < 4; ++i) {
#pragma unroll
        for (int j = 0; j < 4; ++j) {
            const int col = tileN + wn + j * 16 + r16;
            const float bv = bias[col];
#pragma unroll
            for (int r = 0; r < 4; ++r) {
                const int row = tileM + wm + i * 16 + quad * 4 + r;
                float v = acc[i][j][r] + bv;
                if (EPI == 0) {
                    ((unsigned short*)Cp)[(size_t)row * N + col] = f2bf(v);
                } else {
                    ((float*)Cp)[(size_t)row * N + col] = fmaxf(v, 0.0f);
                }
            }
        }
    }
}

// ---------------- scan phase A: per-chunk local end values (2 ch/thread) ----------------
// u: bf16 [B*L, 2D] (re/im interleaved per channel). Eend: [SS][B*D] float2.
__global__ __launch_bounds__(256)
void scanA(const unsigned short* __restrict__ u,
           const float* __restrict__ plog,
           float2* __restrict__ Eend) {
    const int d0 = (blockIdx.x * 256 + threadIdx.x) * 2;
    const int c = blockIdx.y, b = blockIdx.z;
    const float v0  = expf(plog[d0]),      v1  = expf(plog[d0 + 1]);
    const float th0 = expf(plog[DD + d0]), th1 = expf(plog[DD + d0 + 1]);
    const float a0 = expf(-v0), a1 = expf(-v1);
    const float lr0 = a0 * cosf(th0), li0 = a0 * sinf(th0);
    const float lr1 = a1 * cosf(th1), li1 = a1 * sinf(th1);
    float zr0 = 0.f, zi0 = 0.f, zr1 = 0.f, zi1 = 0.f;
    const unsigned short* up = u + (size_t)(b * LL + c * TT) * (2 * DD) + 2 * d0;
#pragma unroll 4
    for (int tl = 0; tl < TT; ++tl) {
        uint2 pr = *(const uint2*)up;
        float xr0 = bf2f((unsigned short)(pr.x & 0xffffu));
        float xi0 = bf2f((unsigned short)(pr.x >> 16));
        float xr1 = bf2f((unsigned short)(pr.y & 0xffffu));
        float xi1 = bf2f((unsigned short)(pr.y >> 16));
        float t;
        t = lr0 * zr0 - li0 * zi0 + xr0; zi0 = lr0 * zi0 + li0 * zr0 + xi0; zr0 = t;
        t = lr1 * zr1 - li1 * zi1 + xr1; zi1 = lr1 * zi1 + li1 * zr1 + xi1; zr1 = t;
        up += 2 * DD;
    }
    *(float4*)&Eend[(size_t)c * (BB * DD) + b * DD + d0] =
        make_float4(zr0, zi0, zr1, zi1);
}

// ---------------- scan phase C: carry prefix + fix-up + gamma (2 ch/thread) ----------------
// xr layout: [B*L, 2D] with col d = gamma*Re(y), col DD+d = gamma*Im(y)
__global__ __launch_bounds__(256)
void scanC(const unsigned short* __restrict__ u,
           const float* __restrict__ plog,
           const float2* __restrict__ Eend,
           unsigned short* __restrict__ xr) {
    const int d0 = (blockIdx.x * 256 + threadIdx.x) * 2;
    const int c = blockIdx.y, b = blockIdx.z;
    const float v0  = expf(plog[d0]),      v1  = expf(plog[d0 + 1]);
    const float th0 = expf(plog[DD + d0]), th1 = expf(plog[DD + d0 + 1]);
    const float g0  = expf(plog[2 * DD + d0]), g1 = expf(plog[2 * DD + d0 + 1]);
    const float a0 = expf(-v0), a1 = expf(-v1);
    const float lr0 = a0 * cosf(th0), li0 = a0 * sinf(th0);
    const float lr1 = a1 * cosf(th1), li1 = a1 * sinf(th1);

    // carry into chunk c: prefix over earlier chunks with Lambda = lambda^TT
    const float aT0 = expf(-(float)TT * v0), aT1 = expf(-(float)TT * v1);
    const float Lr0 = aT0 * cosf((float)TT * th0), Li0 = aT0 * sinf((float)TT * th0);
    const float Lr1 = aT1 * cosf((float)TT * th1), Li1 = aT1 * sinf((float)TT * th1);
    float yr0 = 0.f, yi0 = 0.f, yr1 = 0.f, yi1 = 0.f;
    for (int cc = 0; cc < c; ++cc) {
        float4 e = *(const float4*)&Eend[(size_t)cc * (BB * DD) + b * DD + d0];
        float t;
        t = Lr0 * yr0 - Li0 * yi0 + e.x; yi0 = Lr0 * yi0 + Li0 * yr0 + e.y; yr0 = t;
        t = Lr1 * yr1 - Li1 * yi1 + e.z; yi1 = Lr1 * yi1 + Li1 * yr1 + e.w; yr1 = t;
    }

    const unsigned short* up = u + (size_t)(b * LL + c * TT) * (2 * DD) + 2 * d0;
    unsigned short* xp = xr + (size_t)(b * LL + c * TT) * (2 * DD) + d0;
#pragma unroll 4
    for (int tl = 0; tl < TT; ++tl) {
        uint2 pr = *(const uint2*)up;
        float xr0 = bf2f((unsigned short)(pr.x & 0xffffu));
        float xi0 = bf2f((unsigned short)(pr.x >> 16));
        float xr1 = bf2f((unsigned short)(pr.y & 0xffffu));
        float xi1 = bf2f((unsigned short)(pr.y >> 16));
        float t;
        t = lr0 * yr0 - li0 * yi0 + xr0; yi0 = lr0 * yi0 + li0 * yr0 + xi0; yr0 = t;
        t = lr1 * yr1 - li1 * yi1 + xr1; yi1 = lr1 * yi1 + li1 * yr1 + xi1; yr1 = t;
        *(unsigned int*)&xp[0]  = (unsigned int)f2bf(g0 * yr0) |
                                  ((unsigned int)f2bf(g1 * yr1) << 16);
        *(unsigned int*)&xp[DD] = (unsigned int)f2bf(g0 * yi0) |
                                  ((unsigned int)f2bf(g1 * yi1) << 16);
        up += 2 * DD;
        xp += 2 * DD;
    }
}

extern "C" void kernel_launch(void* const* d_in, const int* in_sizes, int n_in,
                              void* d_out, int out_size, void* d_ws, size_t ws_size,
                              hipStream_t stream) {
    const float* inputs = (const float*)d_in[0];   // B*L*D = 16777216
    const float* Wi     = (const float*)d_in[1];   // 2D*D  = 2097152
    const float* bi     = (const float*)d_in[2];   // 2D
    const float* Wo     = (const float*)d_in[3];   // D*2D  = 2097152
    const float* bo     = (const float*)d_in[4];   // D
    const float* plog   = (const float*)d_in[5];   // 3*D
    float* out = (float*)d_out;

    const size_t M = (size_t)BB * LL;              // 16384
    unsigned short* u_bf  = (unsigned short*)d_ws;             // M*2D bf16  (64 MB)
    unsigned short* xr_bf = u_bf  + M * 2 * DD;                // M*2D bf16  (64 MB)
    unsigned short* in_bf = xr_bf + M * 2 * DD;                // M*D  bf16  (32 MB)
    unsigned short* Wi_bf = in_bf + M * DD;                    // 2D*D bf16  (4 MB)
    unsigned short* Wo_bf = Wi_bf + (size_t)2 * DD * DD;       // D*2D bf16  (4 MB)
    float2* Eend = (float2*)(Wo_bf + (size_t)2 * DD * DD);     // SS*B*D f32x2 (2 MB)

    // merged bf16 casts (inputs + Wi + Wo) in one dispatch
    {
        int total4 = NIN4 + 2 * NW4;
        cast_all_kernel<<<total4 / 256, 256, 0, stream>>>(
            (const float4*)inputs, (ushort4*)in_bf,
            (const float4*)Wi,     (ushort4*)Wi_bf,
            (const float4*)Wo,     (ushort4*)Wo_bf);
    }

    // GEMM1: u[M, 2D] = in_bf[M, D] @ Wi^T + bi   (bf16 out), NT = 16
    gemm_bt<DD, 16, 0><<<(M / 128) * 16, 256, 0, stream>>>(
        in_bf, Wi_bf, bi, (void*)u_bf);

    // scan (2-pass chunked; carries computed inline in scanC), 2 channels/thread
    scanA<<<dim3(DD / 512, SS, BB), 256, 0, stream>>>(u_bf, plog, Eend);
    scanC<<<dim3(DD / 512, SS, BB), 256, 0, stream>>>(u_bf, plog, Eend, xr_bf);

    // GEMM2: out[M, D] = relu(xr[M, 2D] @ Wo^T + bo)  (f32 out), NT = 8
    gemm_bt<2 * DD, 8, 1><<<(M / 128) * 8, 256, 0, stream>>>(
        xr_bf, Wo_bf, bo, (void*)out);
}